// Round 1
// baseline (368.578 us; speedup 1.0000x reference)
//
#include <hip/hip_runtime.h>
#include <hip/hip_bf16.h>
#include <math.h>

#define BB 8
#define NN 4096
#define FF 100
#define DD 64

typedef __bf16 bf16x8 __attribute__((ext_vector_type(8)));
typedef float f32x4 __attribute__((ext_vector_type(4)));

// ---------------------------------------------------------------------------
// Kernel A: hT[b][d][m] = bf16( x[b,m,:] @ Wg[:,d] + bg[d] )   (transposed!)
// Also zeroes the pooled[] accumulator (blocks 0 and 1).
// Block: 256 threads = 4 waves. lane = m offset (coalesced hT writes),
// wave w owns d-range [w*16, w*16+16). Grid: B*N/64 = 512 blocks.
// ---------------------------------------------------------------------------
__global__ __launch_bounds__(256) void kernA(
    const float* __restrict__ x, const float* __restrict__ Wg,
    const float* __restrict__ bg, __bf16* __restrict__ hT,
    float* __restrict__ pooled)
{
    int tid = threadIdx.x;
    int g = blockIdx.x * 256 + tid;
    if (g < BB * DD) pooled[g] = 0.0f;   // covered by blocks 0..1

    int lane = tid & 63;
    int d0   = (tid >> 6) * 16;
    int m0g  = blockIdx.x * 64;          // global row index base
    int b    = m0g >> 12;                // / 4096
    int m    = (m0g & (NN - 1)) + lane;  // row within batch

    const float* xrow = x + ((size_t)b * NN + m) * FF;

    #pragma unroll
    for (int half = 0; half < 2; ++half) {
        int db = d0 + half * 8;
        float acc[8];
        #pragma unroll
        for (int j = 0; j < 8; ++j) acc[j] = bg[db + j];
        #pragma unroll
        for (int f4 = 0; f4 < FF / 4; ++f4) {
            float4 xv = *reinterpret_cast<const float4*>(xrow + f4 * 4);
            const float* wrow = Wg + (f4 * 4) * DD + db;   // broadcast reads
            #pragma unroll
            for (int j = 0; j < 8; ++j) {
                acc[j] += xv.x * wrow[j]
                        + xv.y * wrow[DD + j]
                        + xv.z * wrow[2 * DD + j]
                        + xv.w * wrow[3 * DD + j];
            }
        }
        size_t ob = ((size_t)b * DD + db) * NN + m;
        #pragma unroll
        for (int j = 0; j < 8; ++j)
            hT[ob + (size_t)j * NN] = (__bf16)acc[j];
    }
}

// ---------------------------------------------------------------------------
// Kernel B: S = adj @ h  (bf16 MFMA, fp32 acc), then fused
//           pooled[b][d] += sum_rows( relu(S) * mask )
// Block: 512 threads = 8 waves. Waves 0-3: rows wr*16, d-cols [0,32).
// Waves 4-7: same rows, d-cols [32,64). Block covers 64 rows x 64 cols.
// Grid: (N/64, B) = (64, 8). K-loop over m in steps of 32, reg double-buffer.
// ---------------------------------------------------------------------------
__global__ __launch_bounds__(512) void kernB(
    const float* __restrict__ adj, const __bf16* __restrict__ hT,
    const float* __restrict__ mask, float* __restrict__ pooled)
{
    int b    = blockIdx.y;
    int n0   = blockIdx.x * 64;
    int tid  = threadIdx.x;
    int wave = tid >> 6;
    int lane = tid & 63;
    int wr   = wave & 3;          // row-group (16 rows)
    int wc   = wave >> 2;         // col half: d-base = wc*32
    int l15  = lane & 15;
    int kg   = lane >> 4;         // k-group 0..3 (k = kg*8 + e)

    int row = n0 + wr * 16 + l15;
    const float*  ap  = adj + ((size_t)b * NN + row) * (size_t)NN + kg * 8;
    const __bf16* bpA = hT + ((size_t)b * DD + wc * 32      + l15) * NN + kg * 8;
    const __bf16* bpB = hT + ((size_t)b * DD + wc * 32 + 16 + l15) * NN + kg * 8;

    f32x4 acc0 = {0.f, 0.f, 0.f, 0.f};
    f32x4 acc1 = {0.f, 0.f, 0.f, 0.f};

    float4 a0  = *reinterpret_cast<const float4*>(ap);
    float4 a1  = *reinterpret_cast<const float4*>(ap + 4);
    bf16x8 bv0 = *reinterpret_cast<const bf16x8*>(bpA);
    bf16x8 bv1 = *reinterpret_cast<const bf16x8*>(bpB);

    for (int it = 0; it < NN / 32 - 1; ++it) {
        ap += 32; bpA += 32; bpB += 32;
        float4 na0 = *reinterpret_cast<const float4*>(ap);
        float4 na1 = *reinterpret_cast<const float4*>(ap + 4);
        bf16x8 nb0 = *reinterpret_cast<const bf16x8*>(bpA);
        bf16x8 nb1 = *reinterpret_cast<const bf16x8*>(bpB);

        bf16x8 af;
        af[0] = (__bf16)a0.x; af[1] = (__bf16)a0.y;
        af[2] = (__bf16)a0.z; af[3] = (__bf16)a0.w;
        af[4] = (__bf16)a1.x; af[5] = (__bf16)a1.y;
        af[6] = (__bf16)a1.z; af[7] = (__bf16)a1.w;

        acc0 = __builtin_amdgcn_mfma_f32_16x16x32_bf16(af, bv0, acc0, 0, 0, 0);
        acc1 = __builtin_amdgcn_mfma_f32_16x16x32_bf16(af, bv1, acc1, 0, 0, 0);

        a0 = na0; a1 = na1; bv0 = nb0; bv1 = nb1;
    }
    {
        bf16x8 af;
        af[0] = (__bf16)a0.x; af[1] = (__bf16)a0.y;
        af[2] = (__bf16)a0.z; af[3] = (__bf16)a0.w;
        af[4] = (__bf16)a1.x; af[5] = (__bf16)a1.y;
        af[6] = (__bf16)a1.z; af[7] = (__bf16)a1.w;
        acc0 = __builtin_amdgcn_mfma_f32_16x16x32_bf16(af, bv0, acc0, 0, 0, 0);
        acc1 = __builtin_amdgcn_mfma_f32_16x16x32_bf16(af, bv1, acc1, 0, 0, 0);
    }

    // Epilogue: D layout col = lane&15, row = (lane>>4)*4 + j  [m89 verified]
    int rbase = n0 + wr * 16 + kg * 4;
    float s0 = 0.f, s1 = 0.f;
    #pragma unroll
    for (int j = 0; j < 4; ++j) {
        float mk = mask[b * NN + rbase + j];
        s0 += fmaxf(acc0[j], 0.f) * mk;
        s1 += fmaxf(acc1[j], 0.f) * mk;
    }
    // reduce across the 4 k-groups (lanes differing in bits 4,5): same col
    s0 += __shfl_xor(s0, 16); s0 += __shfl_xor(s0, 32);
    s1 += __shfl_xor(s1, 16); s1 += __shfl_xor(s1, 32);
    if (lane < 16) {
        atomicAdd(&pooled[b * DD + wc * 32 + lane],      s0);
        atomicAdd(&pooled[b * DD + wc * 32 + 16 + lane], s1);
    }
}

// ---------------------------------------------------------------------------
// Kernel C: pooled normalize + time MLP + classifier + sigmoid. 1 block.
// 512 threads: wave w <-> batch b, lane <-> feature d.
// ---------------------------------------------------------------------------
__global__ __launch_bounds__(512) void kernC(
    const float* __restrict__ mask, const float* __restrict__ t_in,
    const float* __restrict__ Wt, const float* __restrict__ bt,
    const float* __restrict__ W0, const float* __restrict__ b0,
    const float* __restrict__ W1, const float* __restrict__ b1,
    const float* __restrict__ W2, const float* __restrict__ b2,
    const float* __restrict__ pooled, float* __restrict__ out)
{
    __shared__ float msum[BB];
    __shared__ float zs[BB][2 * DD];
    __shared__ float z1s[BB][DD];
    __shared__ float z2s[BB][DD];

    int tid  = threadIdx.x;
    int b    = tid >> 6;
    int lane = tid & 63;

    // mask row sums
    float s = 0.f;
    for (int i = lane; i < NN; i += 64) s += mask[b * NN + i];
    s += __shfl_xor(s, 32); s += __shfl_xor(s, 16);
    s += __shfl_xor(s, 8);  s += __shfl_xor(s, 4);
    s += __shfl_xor(s, 2);  s += __shfl_xor(s, 1);
    if (lane == 0) msum[b] = s;
    __syncthreads();

    float ms  = fmaxf(msum[b], 1.0f);
    float pv  = pooled[b * DD + lane] / ms;
    float tev = t_in[b] * Wt[lane] + bt[lane];
    zs[b][lane]      = pv;
    zs[b][DD + lane] = tev;
    __syncthreads();

    float a = b0[lane];
    for (int f = 0; f < 2 * DD; ++f) a += zs[b][f] * W0[f * DD + lane];
    z1s[b][lane] = fmaxf(a, 0.f);
    __syncthreads();

    a = b1[lane];
    for (int f = 0; f < DD; ++f) a += z1s[b][f] * W1[f * DD + lane];
    z2s[b][lane] = fmaxf(a, 0.f);
    __syncthreads();

    if (lane == 0) {
        float o = b2[0];
        for (int f = 0; f < DD; ++f) o += z2s[b][f] * W2[f];
        out[b] = 1.f / (1.f + expf(-o));
    }
}

// ---------------------------------------------------------------------------
extern "C" void kernel_launch(void* const* d_in, const int* in_sizes, int n_in,
                              void* d_out, int out_size, void* d_ws, size_t ws_size,
                              hipStream_t stream)
{
    const float* x    = (const float*)d_in[0];
    const float* adj  = (const float*)d_in[1];
    const float* mask = (const float*)d_in[2];
    const float* t    = (const float*)d_in[3];
    const float* Wg   = (const float*)d_in[4];
    const float* bg   = (const float*)d_in[5];
    const float* Wt   = (const float*)d_in[6];
    const float* bt   = (const float*)d_in[7];
    const float* W0   = (const float*)d_in[8];
    const float* b0   = (const float*)d_in[9];
    const float* W1   = (const float*)d_in[10];
    const float* b1   = (const float*)d_in[11];
    const float* W2   = (const float*)d_in[12];
    const float* b2   = (const float*)d_in[13];
    float* out = (float*)d_out;

    __bf16* hT    = (__bf16*)d_ws;                                  // 4 MB
    float* pooled = (float*)((char*)d_ws + (size_t)BB * DD * NN * 2); // 2 KB

    kernA<<<BB * NN / 64, 256, 0, stream>>>(x, Wg, bg, hT, pooled);
    kernB<<<dim3(NN / 64, BB), 512, 0, stream>>>(adj, hT, mask, pooled);
    kernC<<<1, 512, 0, stream>>>(mask, t, Wt, bt, W0, b0, W1, b1, W2, b2,
                                 pooled, out);
}